// Round 15
// baseline (238.446 us; speedup 1.0000x reference)
//
#include <hip/hip_runtime.h>
#include <cmath>

// ---------------------------------------------------------------------------
// MemoryBankV2: B=128, T=32, D=512, L=2.  Rows = B*T = 4096.
// Round 15: R14 (measured best, 232.7 us) + T1 XCD-aware bijective block
// swizzle on all GEMM grids (each XCD gets a contiguous logical-tile chunk
// -> A/B panel reuse becomes XCD-L2-local).  Everything else frozen.
// ---------------------------------------------------------------------------

#define ROWS 4096
#define DIM  512

typedef __bf16 bf16x8 __attribute__((ext_vector_type(8)));
typedef float  f32x4  __attribute__((ext_vector_type(4)));
typedef unsigned short u16;
typedef u16 u16x4 __attribute__((ext_vector_type(4)));
typedef u16 u16x8 __attribute__((ext_vector_type(8)));

#define RD ((size_t)ROWS * DIM)
#define BUFU 12288   // u16 per LDS buffer: A 64x64 (4096) + B 128x64 (8192)

__device__ __forceinline__ u16 f2bf(float x) {
    union { float f; unsigned u; } c; c.f = x;
    const unsigned r = (c.u + 0x7FFFu + ((c.u >> 16) & 1u)) >> 16;
    return (u16)r;
}
__device__ __forceinline__ float bf2f(u16 h) {
    union { unsigned u; float f; } c; c.u = ((unsigned)h) << 16;
    return c.f;
}

__device__ __forceinline__ void gload16(const void* g, void* l) {
    __builtin_amdgcn_global_load_lds(
        (const __attribute__((address_space(1))) void*)g,
        (__attribute__((address_space(3))) void*)l, 16, 0, 0);
}

__device__ __forceinline__ float gelu_f(float v) {
    return 0.5f * v * (1.0f + erff(v * 0.70710678118654752f));
}

// bijective XCD chunking (m204): dispatch id -> logical tile id so that each
// of the 8 XCDs owns a contiguous logical range.
__device__ __forceinline__ int xcd_swz(int lin, int nwg) {
    const int q = nwg >> 3, r = nwg & 7;
    const int x = lin & 7, i = lin >> 3;
    return (x < r ? x * (q + 1) : r * (q + 1) + (x - r) * q) + i;
}

// ---------------- MFMA GEMM body --------------------------------------------
// C[M,N] = epi(A[M,K] @ B[N,K]^T), K range [kBeg,kEnd), 64x128 tile, BK=64.
// Two-barrier phase per K-step, counted vmcnt(6): 12 loads span barriers.
// EPI: 0: f32 = acc*scale | 1: f32 = acc+bias | 2: bf16 = acc+bias
//      3: bf16 = gelu(acc+bias) | 4: bf16 transposed (C[col*ldc+row]) = acc+bias
//      5: bf16 = visible ? exp(acc*scale) : 0, + per-row atomicAdd of sums
//      6: bf16 = acc*scale (no bias; split-K partials)
// MIX: A rows < 32 read from Amix instead of A (gate attn_out select)
template<int EPI, bool MIX>
__device__ __forceinline__ void mgemm_body(
    const u16* __restrict__ A, int lda,
    const u16* __restrict__ B, int ldb,
    const float* __restrict__ bias,
    void* __restrict__ C, int ldc,
    int kBeg, int kEnd, float scale, int m0, int n0, u16* smem,
    float* __restrict__ sums, const u16* __restrict__ Amix)
{
    const int tid  = threadIdx.x;
    const int lane = tid & 63;
    const int w    = tid >> 6;          // wave 0..3 (2x2 over 64x128 tile)
    const int wr   = (w >> 1) << 5;     // wave row base: 0 or 32
    const int wc   = (w & 1) << 6;      // wave col base: 0 or 64

    f32x4 acc[2][4];
    #pragma unroll
    for (int i = 0; i < 2; ++i)
        #pragma unroll
        for (int j = 0; j < 4; ++j)
            acc[i][j] = (f32x4){0.f, 0.f, 0.f, 0.f};

    // ---- staging map: 24 chunks of 64 slots; wave w owns chunks q*4+w ----
    const u16* gpA[2]; int loA[2];
    #pragma unroll
    for (int q = 0; q < 2; ++q) {
        const int c = (q << 2) + w;
        const int s = (c << 6) + lane;
        const int row = s >> 3, sub = (s & 7) ^ (row & 7);
        const u16* Abase = A;
        if (MIX) Abase = ((m0 + row) < 32) ? Amix : A;
        gpA[q] = Abase + (size_t)(m0 + row) * lda + (sub << 3) + kBeg;
        loA[q] = c << 9;                 // u16 offset
    }
    const u16* gpB[4]; int loB[4];
    #pragma unroll
    for (int q = 0; q < 4; ++q) {
        const int c = ((q + 2) << 2) + w - 8;   // B chunk index in [0,16)
        const int s = (c << 6) + lane;
        const int row = s >> 3, sub = (s & 7) ^ (row & 7);
        gpB[q] = B + (size_t)(n0 + row) * ldb + (sub << 3) + kBeg;
        loB[q] = 4096 + (c << 9);
    }

    // ---- fragment LDS offsets (u16 units, within buffer) ----
    const int l15 = lane & 15, kg = lane >> 4;
    int aoff[2][2], boff[4][2];
    #pragma unroll
    for (int i = 0; i < 2; ++i)
        #pragma unroll
        for (int h = 0; h < 2; ++h) {
            const int r = wr + (i << 4) + l15;
            const int sub = ((h << 2) + kg) ^ (r & 7);
            aoff[i][h] = ((r << 3) + sub) << 3;
        }
    #pragma unroll
    for (int j = 0; j < 4; ++j)
        #pragma unroll
        for (int h = 0; h < 2; ++h) {
            const int r = wc + (j << 4) + l15;
            const int sub = ((h << 2) + kg) ^ (r & 7);
            boff[j][h] = 4096 + (((r << 3) + sub) << 3);
        }

    const int nt = (kEnd - kBeg) >> 6;

    auto STAGE = [&](int t, int bsel) {
        u16* base = smem + bsel * BUFU;
        const int ko = t << 6;
        gload16(gpA[0] + ko, base + loA[0]);
        gload16(gpA[1] + ko, base + loA[1]);
        gload16(gpB[0] + ko, base + loB[0]);
        gload16(gpB[1] + ko, base + loB[1]);
        gload16(gpB[2] + ko, base + loB[2]);
        gload16(gpB[3] + ko, base + loB[3]);
    };

    if (nt > 0) {
        STAGE(0, 0);
        if (nt > 1) STAGE(1, 1);
        for (int t = 0; t < nt; ++t) {
            if (t + 1 < nt) asm volatile("s_waitcnt vmcnt(6)" ::: "memory");
            else            asm volatile("s_waitcnt vmcnt(0)" ::: "memory");
            __builtin_amdgcn_s_barrier();
            asm volatile("" ::: "memory");

            const u16* buf = smem + (t & 1) * BUFU;
            bf16x8 a_[2][2], b_[4][2];
            #pragma unroll
            for (int i = 0; i < 2; ++i)
                #pragma unroll
                for (int h = 0; h < 2; ++h)
                    a_[i][h] = *reinterpret_cast<const bf16x8*>(&buf[aoff[i][h]]);
            #pragma unroll
            for (int j = 0; j < 4; ++j)
                #pragma unroll
                for (int h = 0; h < 2; ++h)
                    b_[j][h] = *reinterpret_cast<const bf16x8*>(&buf[boff[j][h]]);

            asm volatile("s_waitcnt lgkmcnt(0)" ::: "memory");
            __builtin_amdgcn_s_barrier();
            asm volatile("" ::: "memory");

            if (t + 2 < nt) STAGE(t + 2, t & 1);

            __builtin_amdgcn_s_setprio(1);
            #pragma unroll
            for (int h = 0; h < 2; ++h)
                #pragma unroll
                for (int i = 0; i < 2; ++i)
                    #pragma unroll
                    for (int j = 0; j < 4; ++j) {
                        if (EPI == 4)   // unswapped: reg dim = M (transposed store)
                            acc[i][j] = __builtin_amdgcn_mfma_f32_16x16x32_bf16(
                                a_[i][h], b_[j][h], acc[i][j], 0, 0, 0);
                        else            // swapped: reg dim = N (row-major stores)
                            acc[i][j] = __builtin_amdgcn_mfma_f32_16x16x32_bf16(
                                b_[j][h], a_[i][h], acc[i][j], 0, 0, 0);
                    }
            __builtin_amdgcn_s_setprio(0);
        }
    }

    const int lq = lane >> 4;
    if (EPI == 4) {
        // D[m=lq*4+reg][n=l15]; store u16x4 down vT's contiguous token dim
        #pragma unroll
        for (int j = 0; j < 4; ++j) {
            const int col = n0 + wc + (j << 4) + l15;
            const float bj = bias[col];
            #pragma unroll
            for (int i = 0; i < 2; ++i) {
                const int row0 = m0 + wr + (i << 4) + (lq << 2);
                u16x4 pk;
                #pragma unroll
                for (int r = 0; r < 4; ++r) pk[r] = f2bf(acc[i][j][r] + bj);
                *reinterpret_cast<u16x4*>(&((u16*)C)[(size_t)col * ldc + row0]) = pk;
            }
        }
    } else if (EPI == 5) {
        // P = visible ? exp(acc*scale) : 0 (bf16), plus per-row sums.
        float rs0 = 0.f, rs1 = 0.f;
        #pragma unroll
        for (int j = 0; j < 4; ++j) {
            const int col0 = n0 + wc + (j << 4) + (lq << 2);
            #pragma unroll
            for (int i = 0; i < 2; ++i) {
                const int row = m0 + wr + (i << 4) + l15;
                const int lim = (row >> 5) << 5;     // valid cols < lim
                f32x4 v = acc[i][j];
                u16x4 pk;
                float rsl = 0.f;
                #pragma unroll
                for (int r = 0; r < 4; ++r) {
                    const float e = (col0 + r < lim) ? __expf(v[r] * scale) : 0.f;
                    rsl += e;
                    pk[r] = f2bf(e);
                }
                if (i == 0) rs0 += rsl; else rs1 += rsl;
                *reinterpret_cast<u16x4*>(&((u16*)C)[(size_t)row * ldc + col0]) = pk;
            }
        }
        rs0 += __shfl_xor(rs0, 16); rs0 += __shfl_xor(rs0, 32);
        rs1 += __shfl_xor(rs1, 16); rs1 += __shfl_xor(rs1, 32);
        if (lq == 0) {
            atomicAdd(&sums[m0 + wr + l15], rs0);
            atomicAdd(&sums[m0 + wr + 16 + l15], rs1);
        }
    } else {
        // swapped: D[n=lq*4+reg][m=l15] -> reg walks C columns (row-major!)
        #pragma unroll
        for (int j = 0; j < 4; ++j) {
            const int col0 = n0 + wc + (j << 4) + (lq << 2);
            float4 bj = {0.f, 0.f, 0.f, 0.f};
            if (EPI == 1 || EPI == 2 || EPI == 3)
                bj = *reinterpret_cast<const float4*>(&bias[col0]);
            #pragma unroll
            for (int i = 0; i < 2; ++i) {
                const int row = m0 + wr + (i << 4) + l15;
                f32x4 v = acc[i][j];
                if (EPI == 0) {
                    v[0] *= scale; v[1] *= scale; v[2] *= scale; v[3] *= scale;
                    *reinterpret_cast<f32x4*>(&((float*)C)[(size_t)row * ldc + col0]) = v;
                } else if (EPI == 1) {
                    v[0] += bj.x; v[1] += bj.y; v[2] += bj.z; v[3] += bj.w;
                    *reinterpret_cast<f32x4*>(&((float*)C)[(size_t)row * ldc + col0]) = v;
                } else if (EPI == 6) {
                    u16x4 pk = {f2bf(v[0] * scale), f2bf(v[1] * scale),
                                f2bf(v[2] * scale), f2bf(v[3] * scale)};
                    *reinterpret_cast<u16x4*>(&((u16*)C)[(size_t)row * ldc + col0]) = pk;
                } else {
                    v[0] += bj.x; v[1] += bj.y; v[2] += bj.z; v[3] += bj.w;
                    if (EPI == 3) {
                        v[0] = gelu_f(v[0]); v[1] = gelu_f(v[1]);
                        v[2] = gelu_f(v[2]); v[3] = gelu_f(v[3]);
                    }
                    u16x4 pk = {f2bf(v[0]), f2bf(v[1]), f2bf(v[2]), f2bf(v[3])};
                    *reinterpret_cast<u16x4*>(&((u16*)C)[(size_t)row * ldc + col0]) = pk;
                }
            }
        }
    }
}

template<int EPI>
__global__ __launch_bounds__(256, 3) void mgemm(
    const u16* __restrict__ A, int lda, const u16* __restrict__ B, int ldb,
    const float* __restrict__ bias, void* __restrict__ C, int ldc, int K, float scale)
{
    const int lin = blockIdx.x + gridDim.x * blockIdx.y;
    const int s   = xcd_swz(lin, gridDim.x * gridDim.y);
    const int m0 = (s % gridDim.x) << 6;
    const int n0 = (s / gridDim.x) << 7;
    __shared__ u16 smem[2 * BUFU];
    mgemm_body<EPI, false>(A, lda, B, ldb, bias, C, ldc, 0, K, scale, m0, n0,
                           smem, nullptr, nullptr);
}

// block-causal score GEMM + fused exp/mask/rowsum: 64x128 tiles,
// live iff 128*by < 64*bx + 32 (i.e. by <= bx>>1), total 1056.
__device__ __forceinline__ int tri_pref(int b) {
    const int h = b >> 1;
    return (b & 1) ? (h + 1) * (h + 1) : h * (h + 1);
}
__global__ __launch_bounds__(256, 3) void mgemm_tri(
    const u16* __restrict__ A, const u16* __restrict__ B,
    u16* __restrict__ P, float* __restrict__ sums, float scale)
{
    const int z = xcd_swz(blockIdx.x, gridDim.x);
    int bx = 2 * (int)sqrtf((float)z);
    while (tri_pref(bx + 1) <= z) ++bx;
    while (tri_pref(bx) > z) --bx;
    const int by = z - tri_pref(bx);
    __shared__ u16 smem[2 * BUFU];
    mgemm_body<5, false>(A, 512, B, 512, nullptr, P, 4096, 0, 512, scale,
                         bx << 6, by << 7, smem, sums, nullptr);
}

// split-K partial GEMM: writes bf16 acc to Cpart + z*RD.
// AVK: K limit = m0+64 (P has zeros/mask there), chunk balanced per row-block.
template<bool AVK>
__global__ __launch_bounds__(256, 3) void mgemm_pk(
    const u16* __restrict__ A, int lda, const u16* __restrict__ B, int ldb,
    u16* __restrict__ Cpart, int K, int chunk)
{
    const int lin = blockIdx.x + gridDim.x * (blockIdx.y + gridDim.y * blockIdx.z);
    const int s   = xcd_swz(lin, gridDim.x * gridDim.y * gridDim.z);
    const int m0 = (s % gridDim.x) << 6;
    const int rem = s / gridDim.x;
    const int n0 = (rem % gridDim.y) << 7;
    const int z  = rem / gridDim.y;
    const int Klim = AVK ? (m0 + 64) : K;
    const int ch = AVK ? ((((Klim >> 2) + 63) >> 6) << 6) : chunk;
    int kBeg = z * ch; if (kBeg > Klim) kBeg = Klim;
    int kEnd = kBeg + ch; if (kEnd > Klim) kEnd = Klim;
    __shared__ u16 smem[2 * BUFU];
    mgemm_body<6, false>(A, lda, B, ldb, nullptr, Cpart + (size_t)z * RD, 512,
                         kBeg, kEnd, 1.f, m0, n0, smem, nullptr, nullptr);
}

// gate: two K=512 partial halves in one launch (z=0: cf @ Ws[:, :512];
// z=1: attn_out @ Ws[:, 512:], attn_out rows<32 come from cfb via MIX)
__global__ __launch_bounds__(256, 3) void g_gate(
    const u16* __restrict__ cfb, const u16* __restrict__ xbf,
    const u16* __restrict__ Wsb, u16* __restrict__ Cpart)
{
    const int lin = blockIdx.x + gridDim.x * (blockIdx.y + gridDim.y * blockIdx.z);
    const int s   = xcd_swz(lin, gridDim.x * gridDim.y * gridDim.z);
    const int m0 = (s % gridDim.x) << 6;
    const int rem = s / gridDim.x;
    const int n0 = (rem % gridDim.y) << 7;
    const int z  = rem / gridDim.y;
    __shared__ u16 smem[2 * BUFU];
    if (z == 0)
        mgemm_body<6, false>(cfb, 512, Wsb, 1024, nullptr, Cpart, 512,
                             0, 512, 1.f, m0, n0, smem, nullptr, nullptr);
    else
        mgemm_body<6, true>(xbf, 512, Wsb + 512, 1024, nullptr, Cpart + RD, 512,
                            0, 512, 1.f, m0, n0, smem, nullptr, cfb);
}

// fused QKV: logical id y = which*4 + n_block.  q,k: bf16+bias; v: transposed
__global__ __launch_bounds__(256, 3) void qkv_gemm(
    const u16* __restrict__ xa, const u16* __restrict__ cfb,
    const u16* __restrict__ Wqb, const u16* __restrict__ Wkb, const u16* __restrict__ Wvb,
    const float* __restrict__ bq, const float* __restrict__ bk, const float* __restrict__ bv,
    u16* __restrict__ q, u16* __restrict__ k, u16* __restrict__ vT)
{
    __shared__ u16 smem[2 * BUFU];
    const int lin = blockIdx.x + gridDim.x * blockIdx.y;
    const int s   = xcd_swz(lin, gridDim.x * gridDim.y);
    const int m0 = (s % gridDim.x) << 6;
    const int sy = s / gridDim.x;
    const int which = sy >> 2;
    const int n0 = (sy & 3) << 7;
    if (which == 0)
        mgemm_body<2, false>(xa,  512, Wqb, 512, bq, q,  512,  0, 512, 1.f,
                             m0, n0, smem, nullptr, nullptr);
    else if (which == 1)
        mgemm_body<2, false>(cfb, 512, Wkb, 512, bk, k,  512,  0, 512, 1.f,
                             m0, n0, smem, nullptr, nullptr);
    else
        mgemm_body<4, false>(cfb, 512, Wvb, 512, bv, vT, 4096, 0, 512, 1.f,
                             m0, n0, smem, nullptr, nullptr);
}

// --- x = LN(xin + (sum_s bf16 part[s]) * (DIV? 1/sums[row] : 1) (+bias)) ----
// DIV also resets sums[row] to 0 for the next layer's atomic accumulation.
template<int NS, bool HASB, bool DIV>
__global__ __launch_bounds__(256) void ln_res_ps(
    const float* __restrict__ Xin, const u16* __restrict__ partb,
    const float* __restrict__ bias, float* __restrict__ sums,
    const float* __restrict__ gamma, const float* __restrict__ beta,
    float* __restrict__ Xout, u16* __restrict__ Xbf)
{
    const int row  = blockIdx.x * 4 + (threadIdx.x >> 6);
    const int lane = threadIdx.x & 63;
    const float* xr = Xin + (size_t)row * DIM;
    const int d0 = lane << 3;
    const float inv = DIV ? (1.0f / fmaxf(sums[row], 1e-30f)) : 1.0f;
    if (DIV && lane == 0) sums[row] = 0.f;   // reset for next layer

    const float4 x0 = *reinterpret_cast<const float4*>(&xr[d0]);
    const float4 x1 = *reinterpret_cast<const float4*>(&xr[d0 + 4]);
    float a[8] = {0.f, 0.f, 0.f, 0.f, 0.f, 0.f, 0.f, 0.f};
    #pragma unroll
    for (int s = 0; s < NS; ++s) {
        const u16* pr = partb + (size_t)s * RD + (size_t)row * DIM + d0;
        const u16x8 pv = *reinterpret_cast<const u16x8*>(pr);
        #pragma unroll
        for (int i = 0; i < 8; ++i) a[i] += bf2f(pv[i]);
    }
    float v[8] = {x0.x, x0.y, x0.z, x0.w, x1.x, x1.y, x1.z, x1.w};
    #pragma unroll
    for (int i = 0; i < 8; ++i) v[i] += a[i] * inv;
    if (HASB) {
        const float4 b0 = *reinterpret_cast<const float4*>(&bias[d0]);
        const float4 b1 = *reinterpret_cast<const float4*>(&bias[d0 + 4]);
        v[0] += b0.x; v[1] += b0.y; v[2] += b0.z; v[3] += b0.w;
        v[4] += b1.x; v[5] += b1.y; v[6] += b1.z; v[7] += b1.w;
    }

    float sm = 0.f;
    #pragma unroll
    for (int i = 0; i < 8; ++i) sm += v[i];
    #pragma unroll
    for (int off = 32; off; off >>= 1) sm += __shfl_xor(sm, off);
    const float mu = sm * (1.0f / 512.0f);

    float qs = 0.f;
    #pragma unroll
    for (int i = 0; i < 8; ++i) { const float d = v[i] - mu; qs += d * d; }
    #pragma unroll
    for (int off = 32; off; off >>= 1) qs += __shfl_xor(qs, off);
    const float rs = rsqrtf(qs * (1.0f / 512.0f) + 1e-5f);

    const float4 g0 = *reinterpret_cast<const float4*>(&gamma[d0]);
    const float4 g1 = *reinterpret_cast<const float4*>(&gamma[d0 + 4]);
    const float4 b0 = *reinterpret_cast<const float4*>(&beta[d0]);
    const float4 b1 = *reinterpret_cast<const float4*>(&beta[d0 + 4]);
    float o[8];
    o[0] = (v[0] - mu) * rs * g0.x + b0.x;
    o[1] = (v[1] - mu) * rs * g0.y + b0.y;
    o[2] = (v[2] - mu) * rs * g0.z + b0.z;
    o[3] = (v[3] - mu) * rs * g0.w + b0.w;
    o[4] = (v[4] - mu) * rs * g1.x + b1.x;
    o[5] = (v[5] - mu) * rs * g1.y + b1.y;
    o[6] = (v[6] - mu) * rs * g1.z + b1.z;
    o[7] = (v[7] - mu) * rs * g1.w + b1.w;

    float4 f0 = {o[0], o[1], o[2], o[3]}, f1 = {o[4], o[5], o[6], o[7]};
    *reinterpret_cast<float4*>(&Xout[(size_t)row * DIM + d0])     = f0;
    *reinterpret_cast<float4*>(&Xout[(size_t)row * DIM + d0 + 4]) = f1;
    u16x8 ob;
    #pragma unroll
    for (int i = 0; i < 8; ++i) ob[i] = f2bf(o[i]);
    *reinterpret_cast<u16x8*>(&Xbf[(size_t)row * DIM + d0]) = ob;
}

// ---- fused f32->bf16 conversion for 7 arrays + sums zeroing (tail block) ---
struct ConvArgs {
    const float* src[7];
    u16* dst[7];
    int start[8];
    float* sums;
};

__global__ __launch_bounds__(256) void conv_all(ConvArgs a)
{
    const int b = blockIdx.x;
    if (b >= a.start[7]) {               // tail block: zero sums[4096]
        float4* s4 = (float4*)a.sums;
        #pragma unroll
        for (int i = 0; i < 4; ++i)
            s4[threadIdx.x + (i << 8)] = (float4){0.f, 0.f, 0.f, 0.f};
        return;
    }
    int seg = 0;
    #pragma unroll
    for (int i = 1; i < 7; ++i) seg += (a.start[i] <= b) ? 1 : 0;
    const int i = ((b - a.start[seg]) * 256 + threadIdx.x) << 3;
    const float* s = a.src[seg];
    const float4 lo = *reinterpret_cast<const float4*>(&s[i]);
    const float4 hi = *reinterpret_cast<const float4*>(&s[i + 4]);
    u16x8 o = {f2bf(lo.x), f2bf(lo.y), f2bf(lo.z), f2bf(lo.w),
               f2bf(hi.x), f2bf(hi.y), f2bf(hi.z), f2bf(hi.w)};
    *reinterpret_cast<u16x8*>(&a.dst[seg][i]) = o;
}

// ---------------- small helpers ---------------------------------------------
__global__ __launch_bounds__(256) void final_gate_ps(
    float4* __restrict__ out, const float4* __restrict__ cf,
    const float4* __restrict__ x, const u16* __restrict__ partb,
    const float* __restrict__ bias)
{
    const int idx = blockIdx.x * 256 + threadIdx.x;   // 524288 quads of 4
    const int row = idx >> 7;
    const int c4  = idx & 127;
    const float4 zc = cf[idx];
    const u16x4 q0 = *reinterpret_cast<const u16x4*>(&partb[(size_t)idx * 4]);
    const u16x4 q1 = *reinterpret_cast<const u16x4*>(&partb[RD + (size_t)idx * 4]);
    const float4 bb = *reinterpret_cast<const float4*>(&bias[c4 << 2]);
    const float4 za = (row < 32) ? zc : x[idx];
    float4 o;
    { const float g = 1.0f / (1.0f + expf(-(bf2f(q0[0]) + bf2f(q1[0]) + bb.x))); o.x = g * zc.x + (1.0f - g) * za.x; }
    { const float g = 1.0f / (1.0f + expf(-(bf2f(q0[1]) + bf2f(q1[1]) + bb.y))); o.y = g * zc.y + (1.0f - g) * za.y; }
    { const float g = 1.0f / (1.0f + expf(-(bf2f(q0[2]) + bf2f(q1[2]) + bb.z))); o.z = g * zc.z + (1.0f - g) * za.z; }
    { const float g = 1.0f / (1.0f + expf(-(bf2f(q0[3]) + bf2f(q1[3]) + bb.w))); o.w = g * zc.w + (1.0f - g) * za.w; }
    out[idx] = o;
}

// ---------------------------------------------------------------------------
extern "C" void kernel_launch(void* const* d_in, const int* in_sizes, int n_in,
                              void* d_out, int out_size, void* d_ws, size_t ws_size,
                              hipStream_t stream)
{
    const float* cf   = (const float*)d_in[0];
    const float* Wq   = (const float*)d_in[1];
    const float* bq   = (const float*)d_in[2];
    const float* Wk   = (const float*)d_in[3];
    const float* bk   = (const float*)d_in[4];
    const float* Wv   = (const float*)d_in[5];
    const float* bv   = (const float*)d_in[6];
    const float* ln1g = (const float*)d_in[7];
    const float* ln1b = (const float*)d_in[8];
    const float* W1   = (const float*)d_in[9];
    const float* b1   = (const float*)d_in[10];
    const float* W2   = (const float*)d_in[11];
    const float* b2   = (const float*)d_in[12];
    const float* ln2g = (const float*)d_in[13];
    const float* ln2b = (const float*)d_in[14];
    const float* Wsg  = (const float*)d_in[15];
    const float* bsg  = (const float*)d_in[16];
    float* out = (float*)d_out;

    float* ws   = (float*)d_ws;
    float* x    = ws;                               // [4096,512] f32
    float* sums = ws + RD;                          // [4096] f32 (atomic target)
    u16*  partb = (u16*)(ws + 2 * RD);              // 4x[4096,512] bf16 partials
    u16*  pbf  = (u16*)(ws + 10 * RD);              // P [4096,4096] bf16
    u16*  hbf  = (u16*)(ws + 10 * RD);              // h [4096,2048] bf16 (alias)
    u16*  bfb  = (u16*)(ws + 14 * RD);
    u16* cfb = bfb;
    u16* xbf = bfb + RD;
    u16* qbf = bfb + 2 * RD;
    u16* kbf = bfb + 3 * RD;
    u16* vTb = bfb + 4 * RD;                        // [512,4096] (V transposed)
    u16* Wqb = bfb + 5 * RD;
    u16* Wkb = Wqb + 524288;
    u16* Wvb = Wkb + 524288;
    u16* W1b = Wvb + 524288;
    u16* W2b = W1b + 2097152;
    u16* Wsb = W2b + 2097152;

    const float scale = 0.044194173824159216f;      // 1/sqrt(512)

    ConvArgs ca;
    ca.src[0] = cf;  ca.dst[0] = cfb;
    ca.src[1] = Wq;  ca.dst[1] = Wqb;
    ca.src[2] = Wk;  ca.dst[2] = Wkb;
    ca.src[3] = Wv;  ca.dst[3] = Wvb;
    ca.src[4] = W1;  ca.dst[4] = W1b;
    ca.src[5] = W2;  ca.dst[5] = W2b;
    ca.src[6] = Wsg; ca.dst[6] = Wsb;
    ca.start[0] = 0;    ca.start[1] = 1024; ca.start[2] = 1280;
    ca.start[3] = 1536; ca.start[4] = 1792; ca.start[5] = 2816;
    ca.start[6] = 3840; ca.start[7] = 4096;
    ca.sums = sums;
    conv_all<<<4097, 256, 0, stream>>>(ca);          // +1 tail block zeroes sums

    for (int l = 0; l < 2; ++l) {
        const u16* xa = (l == 0) ? cfb : xbf;
        qkv_gemm<<<dim3(64, 12), 256, 0, stream>>>(
            xa, cfb, Wqb + l * 262144, Wkb + l * 262144, Wvb + l * 262144,
            bq + l * 512, bk + l * 512, bv + l * 512, qbf, kbf, vTb);
        // score + exp + mask + rowsum fused (writes bf16 P directly)
        mgemm_tri<<<1056, 256, 0, stream>>>(qbf, kbf, pbf, sums, scale);
        // AV: split-K 4, balanced per row-block, bf16 partials
        mgemm_pk<true><<<dim3(64, 4, 4), 256, 0, stream>>>(
            pbf, 4096, vTb, 4096, partb, 4096, 0);
        ln_res_ps<4, false, true><<<1024, 256, 0, stream>>>(
            (l == 0) ? cf : x, partb, nullptr, sums,
            ln1g + l * 512, ln1b + l * 512, x, xbf);
        mgemm<3><<<dim3(64, 16), 256, 0, stream>>>(
            xbf, 512, W1b + l * 1048576, 512, b1 + l * 2048, hbf, 2048, 512, 1.f);
        // MLP2: split-K 4 x 512, bf16 partials
        mgemm_pk<false><<<dim3(64, 4, 4), 256, 0, stream>>>(
            hbf, 2048, W2b + l * 1048576, 2048, partb, 2048, 512);
        ln_res_ps<4, true, false><<<1024, 256, 0, stream>>>(
            x, partb, b2 + l * 512, nullptr,
            ln2g + l * 512, ln2b + l * 512, x, xbf);
    }

    // gate = [cf | attn_out] @ Ws^T as two K=512 partials in one launch
    g_gate<<<dim3(64, 4, 2), 256, 0, stream>>>(cfb, xbf, Wsb, partb);
    final_gate_ps<<<2048, 256, 0, stream>>>((float4*)out, (const float4*)cf,
                                            (const float4*)x, partb, bsg);
}

// Round 16
// 232.660 us; speedup vs baseline: 1.0249x; 1.0249x over previous
//
#include <hip/hip_runtime.h>
#include <cmath>

// ---------------------------------------------------------------------------
// MemoryBankV2: B=128, T=32, D=512, L=2.  Rows = B*T = 4096.
// FINAL (R14, measured best 232.7 us): R6 GEMM structure (BK=64 two-barrier
// counted-vmcnt, 64x128 tile, 48KB LDS, 3 blocks/CU), fused exp/mask/rowsum
// score epilogue (softmax kernel + f32 S buffer deleted), bf16 split-K
// partials with reductions fused into ln_res/final_gate, merged gate GEMM,
// sums-zeroing folded into conv_all.
// R15's XCD swizzle removed: measured -2.5% (L3-resident working set).
// ---------------------------------------------------------------------------

#define ROWS 4096
#define DIM  512

typedef __bf16 bf16x8 __attribute__((ext_vector_type(8)));
typedef float  f32x4  __attribute__((ext_vector_type(4)));
typedef unsigned short u16;
typedef u16 u16x4 __attribute__((ext_vector_type(4)));
typedef u16 u16x8 __attribute__((ext_vector_type(8)));

#define RD ((size_t)ROWS * DIM)
#define BUFU 12288   // u16 per LDS buffer: A 64x64 (4096) + B 128x64 (8192)

__device__ __forceinline__ u16 f2bf(float x) {
    union { float f; unsigned u; } c; c.f = x;
    const unsigned r = (c.u + 0x7FFFu + ((c.u >> 16) & 1u)) >> 16;
    return (u16)r;
}
__device__ __forceinline__ float bf2f(u16 h) {
    union { unsigned u; float f; } c; c.u = ((unsigned)h) << 16;
    return c.f;
}

__device__ __forceinline__ void gload16(const void* g, void* l) {
    __builtin_amdgcn_global_load_lds(
        (const __attribute__((address_space(1))) void*)g,
        (__attribute__((address_space(3))) void*)l, 16, 0, 0);
}

__device__ __forceinline__ float gelu_f(float v) {
    return 0.5f * v * (1.0f + erff(v * 0.70710678118654752f));
}

// ---------------- MFMA GEMM body --------------------------------------------
// C[M,N] = epi(A[M,K] @ B[N,K]^T), K range [kBeg,kEnd), 64x128 tile, BK=64.
// Two-barrier phase per K-step, counted vmcnt(6): 12 loads span barriers.
// EPI: 0: f32 = acc*scale | 1: f32 = acc+bias | 2: bf16 = acc+bias
//      3: bf16 = gelu(acc+bias) | 4: bf16 transposed (C[col*ldc+row]) = acc+bias
//      5: bf16 = visible ? exp(acc*scale) : 0, + per-row atomicAdd of sums
//      6: bf16 = acc*scale (no bias; split-K partials)
// MIX: A rows < 32 read from Amix instead of A (gate attn_out select)
template<int EPI, bool MIX>
__device__ __forceinline__ void mgemm_body(
    const u16* __restrict__ A, int lda,
    const u16* __restrict__ B, int ldb,
    const float* __restrict__ bias,
    void* __restrict__ C, int ldc,
    int kBeg, int kEnd, float scale, int m0, int n0, u16* smem,
    float* __restrict__ sums, const u16* __restrict__ Amix)
{
    const int tid  = threadIdx.x;
    const int lane = tid & 63;
    const int w    = tid >> 6;          // wave 0..3 (2x2 over 64x128 tile)
    const int wr   = (w >> 1) << 5;     // wave row base: 0 or 32
    const int wc   = (w & 1) << 6;      // wave col base: 0 or 64

    f32x4 acc[2][4];
    #pragma unroll
    for (int i = 0; i < 2; ++i)
        #pragma unroll
        for (int j = 0; j < 4; ++j)
            acc[i][j] = (f32x4){0.f, 0.f, 0.f, 0.f};

    // ---- staging map: 24 chunks of 64 slots; wave w owns chunks q*4+w ----
    const u16* gpA[2]; int loA[2];
    #pragma unroll
    for (int q = 0; q < 2; ++q) {
        const int c = (q << 2) + w;
        const int s = (c << 6) + lane;
        const int row = s >> 3, sub = (s & 7) ^ (row & 7);
        const u16* Abase = A;
        if (MIX) Abase = ((m0 + row) < 32) ? Amix : A;
        gpA[q] = Abase + (size_t)(m0 + row) * lda + (sub << 3) + kBeg;
        loA[q] = c << 9;                 // u16 offset
    }
    const u16* gpB[4]; int loB[4];
    #pragma unroll
    for (int q = 0; q < 4; ++q) {
        const int c = ((q + 2) << 2) + w - 8;   // B chunk index in [0,16)
        const int s = (c << 6) + lane;
        const int row = s >> 3, sub = (s & 7) ^ (row & 7);
        gpB[q] = B + (size_t)(n0 + row) * ldb + (sub << 3) + kBeg;
        loB[q] = 4096 + (c << 9);
    }

    // ---- fragment LDS offsets (u16 units, within buffer) ----
    const int l15 = lane & 15, kg = lane >> 4;
    int aoff[2][2], boff[4][2];
    #pragma unroll
    for (int i = 0; i < 2; ++i)
        #pragma unroll
        for (int h = 0; h < 2; ++h) {
            const int r = wr + (i << 4) + l15;
            const int sub = ((h << 2) + kg) ^ (r & 7);
            aoff[i][h] = ((r << 3) + sub) << 3;
        }
    #pragma unroll
    for (int j = 0; j < 4; ++j)
        #pragma unroll
        for (int h = 0; h < 2; ++h) {
            const int r = wc + (j << 4) + l15;
            const int sub = ((h << 2) + kg) ^ (r & 7);
            boff[j][h] = 4096 + (((r << 3) + sub) << 3);
        }

    const int nt = (kEnd - kBeg) >> 6;

    auto STAGE = [&](int t, int bsel) {
        u16* base = smem + bsel * BUFU;
        const int ko = t << 6;
        gload16(gpA[0] + ko, base + loA[0]);
        gload16(gpA[1] + ko, base + loA[1]);
        gload16(gpB[0] + ko, base + loB[0]);
        gload16(gpB[1] + ko, base + loB[1]);
        gload16(gpB[2] + ko, base + loB[2]);
        gload16(gpB[3] + ko, base + loB[3]);
    };

    if (nt > 0) {
        STAGE(0, 0);
        if (nt > 1) STAGE(1, 1);
        for (int t = 0; t < nt; ++t) {
            if (t + 1 < nt) asm volatile("s_waitcnt vmcnt(6)" ::: "memory");
            else            asm volatile("s_waitcnt vmcnt(0)" ::: "memory");
            __builtin_amdgcn_s_barrier();
            asm volatile("" ::: "memory");

            const u16* buf = smem + (t & 1) * BUFU;
            bf16x8 a_[2][2], b_[4][2];
            #pragma unroll
            for (int i = 0; i < 2; ++i)
                #pragma unroll
                for (int h = 0; h < 2; ++h)
                    a_[i][h] = *reinterpret_cast<const bf16x8*>(&buf[aoff[i][h]]);
            #pragma unroll
            for (int j = 0; j < 4; ++j)
                #pragma unroll
                for (int h = 0; h < 2; ++h)
                    b_[j][h] = *reinterpret_cast<const bf16x8*>(&buf[boff[j][h]]);

            asm volatile("s_waitcnt lgkmcnt(0)" ::: "memory");
            __builtin_amdgcn_s_barrier();
            asm volatile("" ::: "memory");

            if (t + 2 < nt) STAGE(t + 2, t & 1);

            __builtin_amdgcn_s_setprio(1);
            #pragma unroll
            for (int h = 0; h < 2; ++h)
                #pragma unroll
                for (int i = 0; i < 2; ++i)
                    #pragma unroll
                    for (int j = 0; j < 4; ++j) {
                        if (EPI == 4)   // unswapped: reg dim = M (transposed store)
                            acc[i][j] = __builtin_amdgcn_mfma_f32_16x16x32_bf16(
                                a_[i][h], b_[j][h], acc[i][j], 0, 0, 0);
                        else            // swapped: reg dim = N (row-major stores)
                            acc[i][j] = __builtin_amdgcn_mfma_f32_16x16x32_bf16(
                                b_[j][h], a_[i][h], acc[i][j], 0, 0, 0);
                    }
            __builtin_amdgcn_s_setprio(0);
        }
    }

    const int lq = lane >> 4;
    if (EPI == 4) {
        // D[m=lq*4+reg][n=l15]; store u16x4 down vT's contiguous token dim
        #pragma unroll
        for (int j = 0; j < 4; ++j) {
            const int col = n0 + wc + (j << 4) + l15;
            const float bj = bias[col];
            #pragma unroll
            for (int i = 0; i < 2; ++i) {
                const int row0 = m0 + wr + (i << 4) + (lq << 2);
                u16x4 pk;
                #pragma unroll
                for (int r = 0; r < 4; ++r) pk[r] = f2bf(acc[i][j][r] + bj);
                *reinterpret_cast<u16x4*>(&((u16*)C)[(size_t)col * ldc + row0]) = pk;
            }
        }
    } else if (EPI == 5) {
        // P = visible ? exp(acc*scale) : 0 (bf16), plus per-row sums.
        float rs0 = 0.f, rs1 = 0.f;
        #pragma unroll
        for (int j = 0; j < 4; ++j) {
            const int col0 = n0 + wc + (j << 4) + (lq << 2);
            #pragma unroll
            for (int i = 0; i < 2; ++i) {
                const int row = m0 + wr + (i << 4) + l15;
                const int lim = (row >> 5) << 5;     // valid cols < lim
                f32x4 v = acc[i][j];
                u16x4 pk;
                float rsl = 0.f;
                #pragma unroll
                for (int r = 0; r < 4; ++r) {
                    const float e = (col0 + r < lim) ? __expf(v[r] * scale) : 0.f;
                    rsl += e;
                    pk[r] = f2bf(e);
                }
                if (i == 0) rs0 += rsl; else rs1 += rsl;
                *reinterpret_cast<u16x4*>(&((u16*)C)[(size_t)row * ldc + col0]) = pk;
            }
        }
        rs0 += __shfl_xor(rs0, 16); rs0 += __shfl_xor(rs0, 32);
        rs1 += __shfl_xor(rs1, 16); rs1 += __shfl_xor(rs1, 32);
        if (lq == 0) {
            atomicAdd(&sums[m0 + wr + l15], rs0);
            atomicAdd(&sums[m0 + wr + 16 + l15], rs1);
        }
    } else {
        // swapped: D[n=lq*4+reg][m=l15] -> reg walks C columns (row-major!)
        #pragma unroll
        for (int j = 0; j < 4; ++j) {
            const int col0 = n0 + wc + (j << 4) + (lq << 2);
            float4 bj = {0.f, 0.f, 0.f, 0.f};
            if (EPI == 1 || EPI == 2 || EPI == 3)
                bj = *reinterpret_cast<const float4*>(&bias[col0]);
            #pragma unroll
            for (int i = 0; i < 2; ++i) {
                const int row = m0 + wr + (i << 4) + l15;
                f32x4 v = acc[i][j];
                if (EPI == 0) {
                    v[0] *= scale; v[1] *= scale; v[2] *= scale; v[3] *= scale;
                    *reinterpret_cast<f32x4*>(&((float*)C)[(size_t)row * ldc + col0]) = v;
                } else if (EPI == 1) {
                    v[0] += bj.x; v[1] += bj.y; v[2] += bj.z; v[3] += bj.w;
                    *reinterpret_cast<f32x4*>(&((float*)C)[(size_t)row * ldc + col0]) = v;
                } else if (EPI == 6) {
                    u16x4 pk = {f2bf(v[0] * scale), f2bf(v[1] * scale),
                                f2bf(v[2] * scale), f2bf(v[3] * scale)};
                    *reinterpret_cast<u16x4*>(&((u16*)C)[(size_t)row * ldc + col0]) = pk;
                } else {
                    v[0] += bj.x; v[1] += bj.y; v[2] += bj.z; v[3] += bj.w;
                    if (EPI == 3) {
                        v[0] = gelu_f(v[0]); v[1] = gelu_f(v[1]);
                        v[2] = gelu_f(v[2]); v[3] = gelu_f(v[3]);
                    }
                    u16x4 pk = {f2bf(v[0]), f2bf(v[1]), f2bf(v[2]), f2bf(v[3])};
                    *reinterpret_cast<u16x4*>(&((u16*)C)[(size_t)row * ldc + col0]) = pk;
                }
            }
        }
    }
}

template<int EPI>
__global__ __launch_bounds__(256, 3) void mgemm(
    const u16* __restrict__ A, int lda, const u16* __restrict__ B, int ldb,
    const float* __restrict__ bias, void* __restrict__ C, int ldc, int K, float scale)
{
    const int m0 = blockIdx.x << 6;
    const int n0 = blockIdx.y << 7;
    __shared__ u16 smem[2 * BUFU];
    mgemm_body<EPI, false>(A, lda, B, ldb, bias, C, ldc, 0, K, scale, m0, n0,
                           smem, nullptr, nullptr);
}

// block-causal score GEMM + fused exp/mask/rowsum: 64x128 tiles,
// live iff 128*by < 64*bx + 32 (i.e. by <= bx>>1), total 1056.
__device__ __forceinline__ int tri_pref(int b) {
    const int h = b >> 1;
    return (b & 1) ? (h + 1) * (h + 1) : h * (h + 1);
}
__global__ __launch_bounds__(256, 3) void mgemm_tri(
    const u16* __restrict__ A, const u16* __restrict__ B,
    u16* __restrict__ P, float* __restrict__ sums, float scale)
{
    const int z = blockIdx.x;
    int bx = 2 * (int)sqrtf((float)z);
    while (tri_pref(bx + 1) <= z) ++bx;
    while (tri_pref(bx) > z) --bx;
    const int by = z - tri_pref(bx);
    __shared__ u16 smem[2 * BUFU];
    mgemm_body<5, false>(A, 512, B, 512, nullptr, P, 4096, 0, 512, scale,
                         bx << 6, by << 7, smem, sums, nullptr);
}

// split-K partial GEMM: writes bf16 acc to Cpart + z*RD.
// AVK: K limit = m0+64 (P has zeros/mask there), chunk balanced per row-block.
template<bool AVK>
__global__ __launch_bounds__(256, 3) void mgemm_pk(
    const u16* __restrict__ A, int lda, const u16* __restrict__ B, int ldb,
    u16* __restrict__ Cpart, int K, int chunk)
{
    const int m0 = blockIdx.x << 6;
    const int n0 = blockIdx.y << 7;
    const int z  = blockIdx.z;
    const int Klim = AVK ? (m0 + 64) : K;
    const int ch = AVK ? ((((Klim >> 2) + 63) >> 6) << 6) : chunk;
    int kBeg = z * ch; if (kBeg > Klim) kBeg = Klim;
    int kEnd = kBeg + ch; if (kEnd > Klim) kEnd = Klim;
    __shared__ u16 smem[2 * BUFU];
    mgemm_body<6, false>(A, lda, B, ldb, nullptr, Cpart + (size_t)z * RD, 512,
                         kBeg, kEnd, 1.f, m0, n0, smem, nullptr, nullptr);
}

// gate: two K=512 partial halves in one launch (z=0: cf @ Ws[:, :512];
// z=1: attn_out @ Ws[:, 512:], attn_out rows<32 come from cfb via MIX)
__global__ __launch_bounds__(256, 3) void g_gate(
    const u16* __restrict__ cfb, const u16* __restrict__ xbf,
    const u16* __restrict__ Wsb, u16* __restrict__ Cpart)
{
    const int m0 = blockIdx.x << 6;
    const int n0 = blockIdx.y << 7;
    const int z  = blockIdx.z;
    __shared__ u16 smem[2 * BUFU];
    if (z == 0)
        mgemm_body<6, false>(cfb, 512, Wsb, 1024, nullptr, Cpart, 512,
                             0, 512, 1.f, m0, n0, smem, nullptr, nullptr);
    else
        mgemm_body<6, true>(xbf, 512, Wsb + 512, 1024, nullptr, Cpart + RD, 512,
                            0, 512, 1.f, m0, n0, smem, nullptr, cfb);
}

// fused QKV: grid.y = which*4 + n_block.  q,k: bf16+bias; v: bf16+bias transposed
__global__ __launch_bounds__(256, 3) void qkv_gemm(
    const u16* __restrict__ xa, const u16* __restrict__ cfb,
    const u16* __restrict__ Wqb, const u16* __restrict__ Wkb, const u16* __restrict__ Wvb,
    const float* __restrict__ bq, const float* __restrict__ bk, const float* __restrict__ bv,
    u16* __restrict__ q, u16* __restrict__ k, u16* __restrict__ vT)
{
    __shared__ u16 smem[2 * BUFU];
    const int m0 = blockIdx.x << 6;
    const int which = blockIdx.y >> 2;
    const int n0 = (blockIdx.y & 3) << 7;
    if (which == 0)
        mgemm_body<2, false>(xa,  512, Wqb, 512, bq, q,  512,  0, 512, 1.f,
                             m0, n0, smem, nullptr, nullptr);
    else if (which == 1)
        mgemm_body<2, false>(cfb, 512, Wkb, 512, bk, k,  512,  0, 512, 1.f,
                             m0, n0, smem, nullptr, nullptr);
    else
        mgemm_body<4, false>(cfb, 512, Wvb, 512, bv, vT, 4096, 0, 512, 1.f,
                             m0, n0, smem, nullptr, nullptr);
}

// --- x = LN(xin + (sum_s bf16 part[s]) * (DIV? 1/sums[row] : 1) (+bias)) ----
// DIV also resets sums[row] to 0 for the next layer's atomic accumulation.
template<int NS, bool HASB, bool DIV>
__global__ __launch_bounds__(256) void ln_res_ps(
    const float* __restrict__ Xin, const u16* __restrict__ partb,
    const float* __restrict__ bias, float* __restrict__ sums,
    const float* __restrict__ gamma, const float* __restrict__ beta,
    float* __restrict__ Xout, u16* __restrict__ Xbf)
{
    const int row  = blockIdx.x * 4 + (threadIdx.x >> 6);
    const int lane = threadIdx.x & 63;
    const float* xr = Xin + (size_t)row * DIM;
    const int d0 = lane << 3;
    const float inv = DIV ? (1.0f / fmaxf(sums[row], 1e-30f)) : 1.0f;
    if (DIV && lane == 0) sums[row] = 0.f;   // reset for next layer

    const float4 x0 = *reinterpret_cast<const float4*>(&xr[d0]);
    const float4 x1 = *reinterpret_cast<const float4*>(&xr[d0 + 4]);
    float a[8] = {0.f, 0.f, 0.f, 0.f, 0.f, 0.f, 0.f, 0.f};
    #pragma unroll
    for (int s = 0; s < NS; ++s) {
        const u16* pr = partb + (size_t)s * RD + (size_t)row * DIM + d0;
        const u16x8 pv = *reinterpret_cast<const u16x8*>(pr);
        #pragma unroll
        for (int i = 0; i < 8; ++i) a[i] += bf2f(pv[i]);
    }
    float v[8] = {x0.x, x0.y, x0.z, x0.w, x1.x, x1.y, x1.z, x1.w};
    #pragma unroll
    for (int i = 0; i < 8; ++i) v[i] += a[i] * inv;
    if (HASB) {
        const float4 b0 = *reinterpret_cast<const float4*>(&bias[d0]);
        const float4 b1 = *reinterpret_cast<const float4*>(&bias[d0 + 4]);
        v[0] += b0.x; v[1] += b0.y; v[2] += b0.z; v[3] += b0.w;
        v[4] += b1.x; v[5] += b1.y; v[6] += b1.z; v[7] += b1.w;
    }

    float sm = 0.f;
    #pragma unroll
    for (int i = 0; i < 8; ++i) sm += v[i];
    #pragma unroll
    for (int off = 32; off; off >>= 1) sm += __shfl_xor(sm, off);
    const float mu = sm * (1.0f / 512.0f);

    float qs = 0.f;
    #pragma unroll
    for (int i = 0; i < 8; ++i) { const float d = v[i] - mu; qs += d * d; }
    #pragma unroll
    for (int off = 32; off; off >>= 1) qs += __shfl_xor(qs, off);
    const float rs = rsqrtf(qs * (1.0f / 512.0f) + 1e-5f);

    const float4 g0 = *reinterpret_cast<const float4*>(&gamma[d0]);
    const float4 g1 = *reinterpret_cast<const float4*>(&gamma[d0 + 4]);
    const float4 b0 = *reinterpret_cast<const float4*>(&beta[d0]);
    const float4 b1 = *reinterpret_cast<const float4*>(&beta[d0 + 4]);
    float o[8];
    o[0] = (v[0] - mu) * rs * g0.x + b0.x;
    o[1] = (v[1] - mu) * rs * g0.y + b0.y;
    o[2] = (v[2] - mu) * rs * g0.z + b0.z;
    o[3] = (v[3] - mu) * rs * g0.w + b0.w;
    o[4] = (v[4] - mu) * rs * g1.x + b1.x;
    o[5] = (v[5] - mu) * rs * g1.y + b1.y;
    o[6] = (v[6] - mu) * rs * g1.z + b1.z;
    o[7] = (v[7] - mu) * rs * g1.w + b1.w;

    float4 f0 = {o[0], o[1], o[2], o[3]}, f1 = {o[4], o[5], o[6], o[7]};
    *reinterpret_cast<float4*>(&Xout[(size_t)row * DIM + d0])     = f0;
    *reinterpret_cast<float4*>(&Xout[(size_t)row * DIM + d0 + 4]) = f1;
    u16x8 ob;
    #pragma unroll
    for (int i = 0; i < 8; ++i) ob[i] = f2bf(o[i]);
    *reinterpret_cast<u16x8*>(&Xbf[(size_t)row * DIM + d0]) = ob;
}

// ---- fused f32->bf16 conversion for 7 arrays + sums zeroing (tail block) ---
struct ConvArgs {
    const float* src[7];
    u16* dst[7];
    int start[8];
    float* sums;
};

__global__ __launch_bounds__(256) void conv_all(ConvArgs a)
{
    const int b = blockIdx.x;
    if (b >= a.start[7]) {               // tail block: zero sums[4096]
        float4* s4 = (float4*)a.sums;
        #pragma unroll
        for (int i = 0; i < 4; ++i)
            s4[threadIdx.x + (i << 8)] = (float4){0.f, 0.f, 0.f, 0.f};
        return;
    }
    int seg = 0;
    #pragma unroll
    for (int i = 1; i < 7; ++i) seg += (a.start[i] <= b) ? 1 : 0;
    const int i = ((b - a.start[seg]) * 256 + threadIdx.x) << 3;
    const float* s = a.src[seg];
    const float4 lo = *reinterpret_cast<const float4*>(&s[i]);
    const float4 hi = *reinterpret_cast<const float4*>(&s[i + 4]);
    u16x8 o = {f2bf(lo.x), f2bf(lo.y), f2bf(lo.z), f2bf(lo.w),
               f2bf(hi.x), f2bf(hi.y), f2bf(hi.z), f2bf(hi.w)};
    *reinterpret_cast<u16x8*>(&a.dst[seg][i]) = o;
}

// ---------------- small helpers ---------------------------------------------
__global__ __launch_bounds__(256) void final_gate_ps(
    float4* __restrict__ out, const float4* __restrict__ cf,
    const float4* __restrict__ x, const u16* __restrict__ partb,
    const float* __restrict__ bias)
{
    const int idx = blockIdx.x * 256 + threadIdx.x;   // 524288 quads of 4
    const int row = idx >> 7;
    const int c4  = idx & 127;
    const float4 zc = cf[idx];
    const u16x4 q0 = *reinterpret_cast<const u16x4*>(&partb[(size_t)idx * 4]);
    const u16x4 q1 = *reinterpret_cast<const u16x4*>(&partb[RD + (size_t)idx * 4]);
    const float4 bb = *reinterpret_cast<const float4*>(&bias[c4 << 2]);
    const float4 za = (row < 32) ? zc : x[idx];
    float4 o;
    { const float g = 1.0f / (1.0f + expf(-(bf2f(q0[0]) + bf2f(q1[0]) + bb.x))); o.x = g * zc.x + (1.0f - g) * za.x; }
    { const float g = 1.0f / (1.0f + expf(-(bf2f(q0[1]) + bf2f(q1[1]) + bb.y))); o.y = g * zc.y + (1.0f - g) * za.y; }
    { const float g = 1.0f / (1.0f + expf(-(bf2f(q0[2]) + bf2f(q1[2]) + bb.z))); o.z = g * zc.z + (1.0f - g) * za.z; }
    { const float g = 1.0f / (1.0f + expf(-(bf2f(q0[3]) + bf2f(q1[3]) + bb.w))); o.w = g * zc.w + (1.0f - g) * za.w; }
    out[idx] = o;
}

// ---------------------------------------------------------------------------
extern "C" void kernel_launch(void* const* d_in, const int* in_sizes, int n_in,
                              void* d_out, int out_size, void* d_ws, size_t ws_size,
                              hipStream_t stream)
{
    const float* cf   = (const float*)d_in[0];
    const float* Wq   = (const float*)d_in[1];
    const float* bq   = (const float*)d_in[2];
    const float* Wk   = (const float*)d_in[3];
    const float* bk   = (const float*)d_in[4];
    const float* Wv   = (const float*)d_in[5];
    const float* bv   = (const float*)d_in[6];
    const float* ln1g = (const float*)d_in[7];
    const float* ln1b = (const float*)d_in[8];
    const float* W1   = (const float*)d_in[9];
    const float* b1   = (const float*)d_in[10];
    const float* W2   = (const float*)d_in[11];
    const float* b2   = (const float*)d_in[12];
    const float* ln2g = (const float*)d_in[13];
    const float* ln2b = (const float*)d_in[14];
    const float* Wsg  = (const float*)d_in[15];
    const float* bsg  = (const float*)d_in[16];
    float* out = (float*)d_out;

    float* ws   = (float*)d_ws;
    float* x    = ws;                               // [4096,512] f32
    float* sums = ws + RD;                          // [4096] f32 (atomic target)
    u16*  partb = (u16*)(ws + 2 * RD);              // 4x[4096,512] bf16 partials
    u16*  pbf  = (u16*)(ws + 10 * RD);              // P [4096,4096] bf16
    u16*  hbf  = (u16*)(ws + 10 * RD);              // h [4096,2048] bf16 (alias)
    u16*  bfb  = (u16*)(ws + 14 * RD);
    u16* cfb = bfb;
    u16* xbf = bfb + RD;
    u16* qbf = bfb + 2 * RD;
    u16* kbf = bfb + 3 * RD;
    u16* vTb = bfb + 4 * RD;                        // [512,4096] (V transposed)
    u16* Wqb = bfb + 5 * RD;
    u16* Wkb = Wqb + 524288;
    u16* Wvb = Wkb + 524288;
    u16* W1b = Wvb + 524288;
    u16* W2b = W1b + 2097152;
    u16* Wsb = W2b + 2097152;

    const float scale = 0.044194173824159216f;      // 1/sqrt(512)

    ConvArgs ca;
    ca.src[0] = cf;  ca.dst[0] = cfb;
    ca.src[1] = Wq;  ca.dst[1] = Wqb;
    ca.src[2] = Wk;  ca.dst[2] = Wkb;
    ca.src[3] = Wv;  ca.dst[3] = Wvb;
    ca.src[4] = W1;  ca.dst[4] = W1b;
    ca.src[5] = W2;  ca.dst[5] = W2b;
    ca.src[6] = Wsg; ca.dst[6] = Wsb;
    ca.start[0] = 0;    ca.start[1] = 1024; ca.start[2] = 1280;
    ca.start[3] = 1536; ca.start[4] = 1792; ca.start[5] = 2816;
    ca.start[6] = 3840; ca.start[7] = 4096;
    ca.sums = sums;
    conv_all<<<4097, 256, 0, stream>>>(ca);          // +1 tail block zeroes sums

    for (int l = 0; l < 2; ++l) {
        const u16* xa = (l == 0) ? cfb : xbf;
        qkv_gemm<<<dim3(64, 12), 256, 0, stream>>>(
            xa, cfb, Wqb + l * 262144, Wkb + l * 262144, Wvb + l * 262144,
            bq + l * 512, bk + l * 512, bv + l * 512, qbf, kbf, vTb);
        // score + exp + mask + rowsum fused (writes bf16 P directly)
        mgemm_tri<<<1056, 256, 0, stream>>>(qbf, kbf, pbf, sums, scale);
        // AV: split-K 4, balanced per row-block, bf16 partials
        mgemm_pk<true><<<dim3(64, 4, 4), 256, 0, stream>>>(
            pbf, 4096, vTb, 4096, partb, 4096, 0);
        ln_res_ps<4, false, true><<<1024, 256, 0, stream>>>(
            (l == 0) ? cf : x, partb, nullptr, sums,
            ln1g + l * 512, ln1b + l * 512, x, xbf);
        mgemm<3><<<dim3(64, 16), 256, 0, stream>>>(
            xbf, 512, W1b + l * 1048576, 512, b1 + l * 2048, hbf, 2048, 512, 1.f);
        // MLP2: split-K 4 x 512, bf16 partials
        mgemm_pk<false><<<dim3(64, 4, 4), 256, 0, stream>>>(
            hbf, 2048, W2b + l * 1048576, 2048, partb, 2048, 512);
        ln_res_ps<4, true, false><<<1024, 256, 0, stream>>>(
            x, partb, b2 + l * 512, nullptr,
            ln2g + l * 512, ln2b + l * 512, x, xbf);
    }

    // gate = [cf | attn_out] @ Ws^T as two K=512 partials in one launch
    g_gate<<<dim3(64, 4, 2), 256, 0, stream>>>(cfb, xbf, Wsb, partb);
    final_gate_ps<<<2048, 256, 0, stream>>>((float4*)out, (const float4*)cf,
                                            (const float4*)x, partb, bsg);
}